// Round 10
// baseline (157.255 us; speedup 1.0000x reference)
//
#include <hip/hip_runtime.h>
#include <stdint.h>
#include <stddef.h>

// GRIT attention, MI355X bf16-MFMA implementation, round 10.
// softmax_j(q.k*scale + pe[j] - pe[i]) == softmax_j(q.k*scale + pe[j])
// -> flash with per-column additive bias; fixed-max (M=16, exp2 domain) =>
//    LINEAR KV loop; gld16+swizzle+dbuf staging; KV-split x2 + k_comb.
// R10: flash rebuilt on 32x32x16 MFMA (halves LDS frag bytes/FLOP, +20% MFMA
//      ceiling). P^T stays in regs as the PV A-frag via sigma = swap bits 2<->3
//      of kv within each 32-block, baked into vt's column order by the QKV-GEMM
//      epilogue. Additive pe restored (peT), l = per-lane VALU sum + shfl.

typedef unsigned short u16;
typedef __attribute__((ext_vector_type(8))) short short8;
typedef __attribute__((ext_vector_type(8))) unsigned short us8;
typedef __attribute__((ext_vector_type(4))) unsigned short us4;
typedef __attribute__((ext_vector_type(4))) float floatx4;
typedef __attribute__((ext_vector_type(16))) float floatx16;

__device__ __forceinline__ u16 f2b(float f) {
  union { float f; uint32_t u; } v; v.f = f;
  uint32_t u = v.u;
  return (u16)((u + 0x7fffu + ((u >> 16) & 1u)) >> 16);  // RNE
}

// pack two f32 -> two bf16 (round-half-up): add, add, v_perm
__device__ __forceinline__ uint32_t pkbf16(float a, float b) {
  union { float f; uint32_t u; } x, y; x.f = a; y.f = b;
  return __builtin_amdgcn_perm(y.u + 0x8000u, x.u + 0x8000u, 0x07060302u);
}

#if __has_builtin(__builtin_amdgcn_exp2f)
__device__ __forceinline__ float fexp2(float x) { return __builtin_amdgcn_exp2f(x); }
#else
__device__ __forceinline__ float fexp2(float x) { return exp2f(x); }
#endif

__device__ __forceinline__ void gld16(const u16* g, u16* l) {
  __builtin_amdgcn_global_load_lds(
      (const __attribute__((address_space(1))) uint32_t*)(const void*)g,
      (__attribute__((address_space(3))) uint32_t*)(void*)l, 16, 0, 0);
}

__device__ __forceinline__ floatx16 zero16() {
  floatx16 v;
#pragma unroll
  for (int i = 0; i < 16; ++i) v[i] = 0.0f;
  return v;
}

// ---------------- fused prep ----------------

__device__ __forceinline__ void tr_tile(const float* __restrict__ in,
                                        u16* __restrict__ out, int R, int C,
                                        int bx, int by, u16 (*tile)[33]) {
  int tx = threadIdx.x & 31, ty = threadIdx.x >> 5;
  int c0 = bx * 32, r0 = by * 32;
#pragma unroll
  for (int i = 0; i < 32; i += 8)
    tile[ty + i][tx] = f2b(in[(size_t)(r0 + ty + i) * C + c0 + tx]);
  __syncthreads();
#pragma unroll
  for (int i = 0; i < 32; i += 8)
    out[(size_t)(c0 + ty + i) * R + r0 + tx] = tile[tx][ty + i];
}

__global__ __launch_bounds__(256) void k_prep(
    const float* __restrict__ x, u16* __restrict__ xb,
    const float* __restrict__ w_qkv, u16* __restrict__ wqkvT,
    const float* __restrict__ w_out, u16* __restrict__ woutT,
    const float* __restrict__ pe, const float* __restrict__ w_pe,
    const float* __restrict__ b_pe, float* __restrict__ peT) {
  __shared__ u16 tile[32][33];
  int b = blockIdx.x;
  if (b < 2048) {
    int i = b * 256 + threadIdx.x;
    float4 v = ((const float4*)x)[i];
    uint2 o = make_uint2(pkbf16(v.x, v.y), pkbf16(v.z, v.w));
    ((uint2*)xb)[i] = o;
  } else if (b < 2816) {
    int idx = b - 2048;
    tr_tile(w_qkv, wqkvT, 512, 1536, idx % 48, idx / 48, tile);
  } else if (b < 3072) {
    int idx = b - 2816;
    tr_tile(w_out, woutT, 512, 512, idx % 16, idx / 16, tile);
  } else {
    int idx = (b - 3072) * 256 + threadIdx.x;
    int h = idx >> 12, n = idx & 4095;
    float acc = b_pe[h];
#pragma unroll
    for (int d = 0; d < 16; ++d) acc = fmaf(pe[n * 16 + d], w_pe[d * 8 + h], acc);
    peT[h * 4096 + n] = acc * 1.4426950408889634f - 16.0f;
  }
}

// ---------------- QKV GEMM: 64x128 tile, BK=64, 512 thr, async dbuf ---------
// Q cols (<512) pre-scaled by 0.125*log2e; V cols -> vtp[d][4096] transposed
// with sigma (swap bits 2<->3 of n within each 32-block) for the flash PV frag.

__global__ __launch_bounds__(512, 6) void k_gemm_qkv(const u16* __restrict__ A,
                                                     const u16* __restrict__ Bt,
                                                     const float* __restrict__ bias,
                                                     u16* __restrict__ qk,
                                                     u16* __restrict__ vtp) {
  __shared__ __align__(16) u16 smem[24576];  // As 2x4096 @0, Bs 2x8192 @8192
  const int tid = threadIdx.x;
  const int lane = tid & 63, wave = tid >> 6;
  const int colx = lane & 15, quad = lane >> 4;
  const int m0 = blockIdx.y * 64, n0 = blockIdx.x * 128;
  const int wm = wave >> 2, wn = wave & 3;
  const int sc = (lane & 7) ^ ((lane >> 3) & 7);
  const floatx4 fz = {0.f, 0.f, 0.f, 0.f};
  floatx4 acc[2][2];
#pragma unroll
  for (int i = 0; i < 2; ++i)
#pragma unroll
    for (int j = 0; j < 2; ++j) acc[i][j] = fz;

#define PREF_QKV(k0, b)                                                       \
  {                                                                           \
    int rowa = wave * 8 + (lane >> 3);                                        \
    gld16(&A[(size_t)(m0 + rowa) * 512 + (k0) + sc * 8],                      \
          &smem[(b) * 4096 + wave * 512 + lane * 8]);                         \
    _Pragma("unroll") for (int c = 0; c < 2; ++c) {                           \
      int rowb = wave * 16 + c * 8 + (lane >> 3);                             \
      gld16(&Bt[(size_t)(n0 + rowb) * 512 + (k0) + sc * 8],                   \
            &smem[8192 + (b) * 8192 + wave * 1024 + c * 512 + lane * 8]);     \
    }                                                                         \
  }

  PREF_QKV(0, 0);
  __syncthreads();
  for (int it = 0; it < 8; ++it) {
    int cur = it & 1;
    if (it < 7) PREF_QKV((it + 1) * 64, cur ^ 1);
    const u16* As = &smem[cur * 4096];
    const u16* Bs = &smem[8192 + cur * 8192];
#pragma unroll
    for (int kk = 0; kk < 2; ++kk) {
      short8 af[2], bf[2];
#pragma unroll
      for (int i = 0; i < 2; ++i) {
        int row = wm * 32 + i * 16 + colx;
        af[i] = *(const short8*)&As[row * 64 + (((kk * 4 + quad) ^ (colx & 7))) * 8];
      }
#pragma unroll
      for (int j = 0; j < 2; ++j) {
        int row = wn * 32 + j * 16 + colx;
        bf[j] = *(const short8*)&Bs[row * 64 + (((kk * 4 + quad) ^ (colx & 7))) * 8];
      }
#pragma unroll
      for (int i = 0; i < 2; ++i)
#pragma unroll
        for (int j = 0; j < 2; ++j)
          acc[i][j] = __builtin_amdgcn_mfma_f32_16x16x32_bf16(af[i], bf[j], acc[i][j], 0, 0, 0);
    }
    __syncthreads();
  }

  const bool isV = (blockIdx.x >= 8);
  const int qsw = ((quad & 1) << 1) | (quad >> 1);  // sigma on the quad bits
#pragma unroll
  for (int j = 0; j < 2; ++j) {
    int c = n0 + wn * 32 + j * 16 + colx;
    float bq = bias[c];
    if (!isV) {
      float qs = (c < 512) ? 0.18033688011112042f : 1.0f;  // 0.125*log2(e)
#pragma unroll
      for (int i = 0; i < 2; ++i)
#pragma unroll
        for (int r = 0; r < 4; ++r) {
          int row = m0 + wm * 32 + i * 16 + quad * 4 + r;
          qk[(size_t)row * 1024 + c] = f2b((acc[i][j][r] + bq) * qs);
        }
    } else {
      int d = c - 1024;
#pragma unroll
      for (int i = 0; i < 2; ++i) {
        us4 o;
#pragma unroll
        for (int r = 0; r < 4; ++r) o[r] = f2b(acc[i][j][r] + bq);
        *(us4*)&vtp[(size_t)d * 4096 + m0 + wm * 32 + i * 16 + qsw * 4] = o;
      }
    }
  }
#undef PREF_QKV
}

// ---------------- flash (32x32 MFMA, fixed-max, linear, KV-split x2) --------
// grid (64 q-tiles, 8 heads, 2 kv-splits), 256 thr = 4 waves = 2 ih x 2 jq.
// Per wave-iter: S^T 32kv x 32q x 64d = 4 MFMAs; exp/pack; PV 4 MFMAs.
// C-layout: q=lane&31, kv=(reg&3)+8*(reg>>2)+4*(lane>>5) -> P is the PV A-frag
// under sigma. LDS = 40960 B exactly: Q 8KB, K dbuf 16KB, V dbuf 16KB.

__global__ __launch_bounds__(256, 4) void k_flash(const u16* __restrict__ qk,
                                                  const u16* __restrict__ vt,
                                                  const float* __restrict__ peT,
                                                  float* __restrict__ opart,
                                                  float* __restrict__ lpart) {
  __shared__ __align__(16) u16 smem[20480];  // 40960 B
  float* bufs = (float*)smem;                // epilogue overlay 2 x 32x65 f32

  const int tid = threadIdx.x;
  const int lane = tid & 63, wave = tid >> 6;
  const int n31 = lane & 31, L = lane >> 5;
  const int ih = wave >> 1, jq = wave & 1;
  const int q0 = blockIdx.x * 64;
  const int h = blockIdx.y;
  const int z = blockIdx.z;
  const int kvb = z * 2048;

  const int sc = (lane & 7) ^ ((lane >> 3) & 7);
  const int sr = lane >> 3;  // staging row low bits

  // stage Q (swizzled ds_write): 64 rows x 64 d
#pragma unroll
  for (int rr = 0; rr < 2; ++rr) {
    int idx = rr * 256 + tid;
    int row = idx >> 3, ch = idx & 7;
    *(us8*)&smem[row * 64 + (ch ^ (row & 7)) * 8] =
        *(const us8*)&qk[(size_t)(q0 + row) * 1024 + h * 64 + ch * 8];
  }
  // prefetch KV tile 0
  const u16* qptr = qk + (size_t)kvb * 1024 + 512 + h * 64 + sc * 8;
  const u16* vptr = vt + (size_t)(h * 64) * 4096 + kvb + sc * 8;
#pragma unroll
  for (int rr = 0; rr < 2; ++rr) {
    int row = rr * 32 + wave * 8 + sr;
    gld16(qptr + (size_t)row * 1024, &smem[4096 + rr * 2048 + wave * 512 + lane * 8]);
    gld16(vptr + (size_t)row * 4096, &smem[12288 + rr * 2048 + wave * 512 + lane * 8]);
  }
  qptr += 65536;  // next 64 kv rows
  vptr += 64;     // next 64 kv cols
  const float* pptr = peT + h * 4096 + kvb + jq * 32 + 4 * L;
  __syncthreads();

  // loop-invariant Q B-frags: B[k=d][n=q], q = ih*32+n31, d = dc*16 + L*8 + j
  short8 qf[4];
  {
    int row = ih * 32 + n31, r7 = row & 7;
#pragma unroll
    for (int dc = 0; dc < 4; ++dc)
      qf[dc] = *(const short8*)&smem[row * 64 + (((dc * 2 + L) ^ r7)) * 8];
  }

  floatx16 oacc0 = zero16(), oacc1 = zero16();
  float rsum = 0.0f;

  for (int it = 0; it < 32; ++it) {
    const int cur = it & 1;
    floatx4 pev[4];
#pragma unroll
    for (int c4 = 0; c4 < 4; ++c4)
      pev[c4] = *(const floatx4*)(pptr + c4 * 8);
    pptr += 64;
    if (it < 31) {
#pragma unroll
      for (int rr = 0; rr < 2; ++rr) {
        int row = rr * 32 + wave * 8 + sr;
        gld16(qptr + (size_t)row * 1024,
              &smem[4096 + (cur ^ 1) * 4096 + rr * 2048 + wave * 512 + lane * 8]);
        gld16(vptr + (size_t)row * 4096,
              &smem[12288 + (cur ^ 1) * 4096 + rr * 2048 + wave * 512 + lane * 8]);
      }
      qptr += 65536;
      vptr += 64;
    }
    const u16* Ks = &smem[4096 + cur * 4096];
    const u16* Vts = &smem[12288 + cur * 4096];

    // S^T: A=K (m=kv), B=Q (n=q); d in 4 chunks of 16
    floatx16 sacc = zero16();
    {
      int row = jq * 32 + n31, r7 = row & 7;
#pragma unroll
      for (int dc = 0; dc < 4; ++dc) {
        short8 kf = *(const short8*)&Ks[row * 64 + (((dc * 2 + L) ^ r7)) * 8];
        sacc = __builtin_amdgcn_mfma_f32_32x32x16_bf16(kf, qf[dc], sacc, 0, 0, 0);
      }
    }
    // p = exp2(s + pe); l partial on VALU; pack into PV A-frags
    union { uint32_t w[8]; short8 s[2]; } pk;
#pragma unroll
    for (int c4 = 0; c4 < 4; ++c4) {
      float p0 = fexp2(sacc[c4 * 4 + 0] + pev[c4][0]);
      float p1 = fexp2(sacc[c4 * 4 + 1] + pev[c4][1]);
      float p2 = fexp2(sacc[c4 * 4 + 2] + pev[c4][2]);
      float p3 = fexp2(sacc[c4 * 4 + 3] + pev[c4][3]);
      rsum += (p0 + p1) + (p2 + p3);
      pk.w[c4 * 2 + 0] = pkbf16(p0, p1);
      pk.w[c4 * 2 + 1] = pkbf16(p2, p3);
    }
    // PV: A=P (m=q), B=V' (n=d); kv 32 (jq's) = 2 K=16 MFMAs per 32-d block
#pragma unroll
    for (int m01 = 0; m01 < 2; ++m01) {
      int ch = jq * 4 + m01 * 2 + L;
      {
        int row = n31, r7 = row & 7;
        short8 vf = *(const short8*)&Vts[row * 64 + ((ch ^ r7)) * 8];
        oacc0 = __builtin_amdgcn_mfma_f32_32x32x16_bf16(pk.s[m01], vf, oacc0, 0, 0, 0);
      }
      {
        int row = 32 + n31, r7 = row & 7;
        short8 vf = *(const short8*)&Vts[row * 64 + ((ch ^ r7)) * 8];
        oacc1 = __builtin_amdgcn_mfma_f32_32x32x16_bf16(pk.s[m01], vf, oacc1, 0, 0, 0);
      }
    }
    __syncthreads();
  }

  // l over both L halves -> every lane holds l_jq(q = n31)
  rsum += __shfl_xor(rsum, 32);

  // cross-jq reduction in LDS (K/V buffers dead)
  float* b = bufs + ih * 2080;
  if (jq == 1) {
#pragma unroll
    for (int reg = 0; reg < 16; ++reg) {
      int qr = (reg & 3) + 8 * (reg >> 2) + 4 * L;
      b[qr * 65 + n31] = oacc0[reg];
      b[qr * 65 + 32 + n31] = oacc1[reg];
    }
    if (L == 0) b[n31 * 65 + 64] = rsum;
  }
  __syncthreads();
  if (jq == 0) {
#pragma unroll
    for (int reg = 0; reg < 16; ++reg) {
      int qr = (reg & 3) + 8 * (reg >> 2) + 4 * L;
      oacc0[reg] += b[qr * 65 + n31];
      oacc1[reg] += b[qr * 65 + 32 + n31];
    }
    rsum += b[n31 * 65 + 64];
    float* op = opart + (size_t)z * 2097152;
#pragma unroll
    for (int reg = 0; reg < 16; ++reg) {
      int qr = (reg & 3) + 8 * (reg >> 2) + 4 * L;
      size_t base = (size_t)(q0 + ih * 32 + qr) * 512 + h * 64;
      op[base + n31] = oacc0[reg];
      op[base + 32 + n31] = oacc1[reg];
    }
    if (L == 0)
      lpart[z * 32768 + h * 4096 + q0 + ih * 32 + n31] = rsum;
  }
}

// ---------------- combine: ao = (O0+O1)/(l0+l1), bf16 ----------------

__global__ __launch_bounds__(256) void k_comb(const float* __restrict__ opart,
                                              const float* __restrict__ lpart,
                                              u16* __restrict__ ao) {
  int idx = blockIdx.x * 256 + threadIdx.x;     // 524288 = 4096 * 128
  int n = idx >> 7, d4 = idx & 127;
  int h = d4 >> 4;
  float l = lpart[h * 4096 + n] + lpart[32768 + h * 4096 + n];
  float inv = 1.0f / l;
  float4 o0 = *(const float4*)&opart[(size_t)n * 512 + d4 * 4];
  float4 o1 = *(const float4*)&opart[2097152 + (size_t)n * 512 + d4 * 4];
  us4 o;
  o[0] = f2b((o0.x + o1.x) * inv);
  o[1] = f2b((o0.y + o1.y) * inv);
  o[2] = f2b((o0.z + o1.z) * inv);
  o[3] = f2b((o0.w + o1.w) * inv);
  *(us4*)&ao[(size_t)n * 512 + d4 * 4] = o;
}

// ---------------- out GEMM: 64x64 tile, BK=64, 512 thr, async dbuf ----------

__global__ __launch_bounds__(512, 4) void k_gemm_out(const u16* __restrict__ A,
                                                     const u16* __restrict__ Bt,
                                                     const float* __restrict__ bias,
                                                     float* __restrict__ Cout) {
  __shared__ __align__(16) u16 smem[16384];  // As 2x4096 @0, Bs 2x4096 @8192
  const int tid = threadIdx.x;
  const int lane = tid & 63, wave = tid >> 6;
  const int colx = lane & 15, quad = lane >> 4;
  const int m0 = blockIdx.y * 64, n0 = blockIdx.x * 64;
  const int wm = wave >> 2, wn = wave & 3;
  const int sc = (lane & 7) ^ ((lane >> 3) & 7);
  const floatx4 fz = {0.f, 0.f, 0.f, 0.f};
  floatx4 acc[2];
  acc[0] = fz; acc[1] = fz;

#define PREF_OUT(k0, b)                                                       \
  {                                                                           \
    int rowa = wave * 8 + (lane >> 3);                                        \
    gld16(&A[(size_t)(m0 + rowa) * 512 + (k0) + sc * 8],                      \
          &smem[(b) * 4096 + wave * 512 + lane * 8]);                         \
    gld16(&Bt[(size_t)(n0 + rowa) * 512 + (k0) + sc * 8],                     \
          &smem[8192 + (b) * 4096 + wave * 512 + lane * 8]);                  \
  }

  PREF_OUT(0, 0);
  __syncthreads();
  for (int it = 0; it < 8; ++it) {
    int cur = it & 1;
    if (it < 7) PREF_OUT((it + 1) * 64, cur ^ 1);
    const u16* As = &smem[cur * 4096];
    const u16* Bs = &smem[8192 + cur * 4096];
#pragma unroll
    for (int kk = 0; kk < 2; ++kk) {
      short8 af[2], bf;
#pragma unroll
      for (int i = 0; i < 2; ++i) {
        int row = wm * 32 + i * 16 + colx;
        af[i] = *(const short8*)&As[row * 64 + (((kk * 4 + quad) ^ (colx & 7))) * 8];
      }
      {
        int row = wn * 16 + colx;
        bf = *(const short8*)&Bs[row * 64 + (((kk * 4 + quad) ^ (colx & 7))) * 8];
      }
#pragma unroll
      for (int i = 0; i < 2; ++i)
        acc[i] = __builtin_amdgcn_mfma_f32_16x16x32_bf16(af[i], bf, acc[i], 0, 0, 0);
    }
    __syncthreads();
  }
  int c = n0 + wn * 16 + colx;
  float bq = bias[c];
#pragma unroll
  for (int i = 0; i < 2; ++i)
#pragma unroll
    for (int r = 0; r < 4; ++r) {
      int row = m0 + wm * 32 + i * 16 + quad * 4 + r;
      Cout[(size_t)row * 512 + c] = acc[i][r] + bq;
    }
#undef PREF_OUT
}

// ---------------- launch ----------------

extern "C" void kernel_launch(void* const* d_in, const int* in_sizes, int n_in,
                              void* d_out, int out_size, void* d_ws, size_t ws_size,
                              hipStream_t stream) {
  const float* x     = (const float*)d_in[0];
  const float* pe    = (const float*)d_in[1];
  const float* w_qkv = (const float*)d_in[2];
  const float* b_qkv = (const float*)d_in[3];
  const float* w_pe  = (const float*)d_in[4];
  const float* b_pe  = (const float*)d_in[5];
  const float* w_out = (const float*)d_in[6];
  const float* b_out = (const float*)d_in[7];
  float* out = (float*)d_out;

  // workspace layout
  u16* xb    = (u16*)d_ws;              // 4096*512
  u16* wqkvT = xb    + 2097152;         // 1536*512
  u16* woutT = wqkvT + 786432;          // 512*512
  u16* qk    = woutT + 262144;          // 4096*1024 (Q'|K)
  u16* vt    = qk    + 4194304;         // 512*4096 (sigma-permuted V^T)
  u16* ao    = vt    + 2097152;         // 4096*512 bf16
  float* peT   = (float*)(ao + 2097152); // 8*4096 f32
  float* opart = peT + 32768;           // 2 * 4096*512 f32
  float* lpart = opart + 4194304;       // 2 * 8*4096 f32

  k_prep<<<3200, 256, 0, stream>>>(x, xb, w_qkv, wqkvT, w_out, woutT,
                                   pe, w_pe, b_pe, peT);
  k_gemm_qkv<<<dim3(12, 64), 512, 0, stream>>>(xb, wqkvT, b_qkv, qk, vt);
  k_flash<<<dim3(64, 8, 2), 256, 0, stream>>>(qk, vt, peT, opart, lpart);
  k_comb<<<2048, 256, 0, stream>>>(opart, lpart, ao);
  k_gemm_out<<<dim3(8, 64), 512, 0, stream>>>(ao, woutT, b_out, out);
}

// Round 12
// 142.169 us; speedup vs baseline: 1.1061x; 1.1061x over previous
//
#include <hip/hip_runtime.h>
#include <stdint.h>
#include <stddef.h>

// GRIT attention, MI355X bf16-MFMA implementation, round 12.
// = R9 (best flash: 16x16 MFMA, w-fold, x2 unroll, incremental pointers)
// + R11: k_gemm_qkv V epilogue via LDS transpose buffer -> coalesced us8 stores
// + R12: fix R11 bug — head index for wexp must include the n0-1024 offset
//   (R11 used local d only, folding wrong heads' w~ for blocks 9..11).

typedef unsigned short u16;
typedef __attribute__((ext_vector_type(8))) short short8;
typedef __attribute__((ext_vector_type(8))) unsigned short us8;
typedef __attribute__((ext_vector_type(4))) unsigned short us4;
typedef __attribute__((ext_vector_type(4))) float floatx4;

__device__ __forceinline__ u16 f2b(float f) {
  union { float f; uint32_t u; } v; v.f = f;
  uint32_t u = v.u;
  return (u16)((u + 0x7fffu + ((u >> 16) & 1u)) >> 16);  // RNE
}

// pack two f32 -> two bf16 (round-half-up): add, add, v_perm
__device__ __forceinline__ uint32_t pkbf16(float a, float b) {
  union { float f; uint32_t u; } x, y; x.f = a; y.f = b;
  return __builtin_amdgcn_perm(y.u + 0x8000u, x.u + 0x8000u, 0x07060302u);
}

#if __has_builtin(__builtin_amdgcn_exp2f)
__device__ __forceinline__ float fexp2(float x) { return __builtin_amdgcn_exp2f(x); }
#else
__device__ __forceinline__ float fexp2(float x) { return exp2f(x); }
#endif

__device__ __forceinline__ void gld16(const u16* g, u16* l) {
  __builtin_amdgcn_global_load_lds(
      (const __attribute__((address_space(1))) uint32_t*)(const void*)g,
      (__attribute__((address_space(3))) uint32_t*)(void*)l, 16, 0, 0);
}

// ---------------- fused prep ----------------

__device__ __forceinline__ void tr_tile(const float* __restrict__ in,
                                        u16* __restrict__ out, int R, int C,
                                        int bx, int by, u16 (*tile)[33]) {
  int tx = threadIdx.x & 31, ty = threadIdx.x >> 5;
  int c0 = bx * 32, r0 = by * 32;
#pragma unroll
  for (int i = 0; i < 32; i += 8)
    tile[ty + i][tx] = f2b(in[(size_t)(r0 + ty + i) * C + c0 + tx]);
  __syncthreads();
#pragma unroll
  for (int i = 0; i < 32; i += 8)
    out[(size_t)(c0 + ty + i) * R + r0 + tx] = tile[tx][ty + i];
}

__global__ __launch_bounds__(256) void k_prep(
    const float* __restrict__ x, u16* __restrict__ xb,
    const float* __restrict__ w_qkv, u16* __restrict__ wqkvT,
    const float* __restrict__ w_out, u16* __restrict__ woutT,
    const float* __restrict__ pe, const float* __restrict__ w_pe,
    const float* __restrict__ b_pe, float* __restrict__ wexp,
    u16* __restrict__ wpb) {
  __shared__ u16 tile[32][33];
  int b = blockIdx.x;
  if (b < 2048) {
    int i = b * 256 + threadIdx.x;
    float4 v = ((const float4*)x)[i];
    uint2 o = make_uint2(pkbf16(v.x, v.y), pkbf16(v.z, v.w));
    ((uint2*)xb)[i] = o;
  } else if (b < 2816) {
    int idx = b - 2048;
    tr_tile(w_qkv, wqkvT, 512, 1536, idx % 48, idx / 48, tile);
  } else if (b < 3072) {
    int idx = b - 2816;
    tr_tile(w_out, woutT, 512, 512, idx % 16, idx / 16, tile);
  } else {
    int idx = (b - 3072) * 256 + threadIdx.x;
    int h = idx >> 12, n = idx & 4095;
    float acc = b_pe[h];
#pragma unroll
    for (int d = 0; d < 16; ++d) acc = fmaf(pe[n * 16 + d], w_pe[d * 8 + h], acc);
    float w = exp2f(acc * 1.4426950408889634f - 16.0f);
    u16 wb = f2b(w);
    union { uint32_t u; float f; } cv; cv.u = ((uint32_t)wb) << 16;
    wexp[h * 4096 + n] = cv.f;  // the SAME bf16-rounded value V' will use
    int pn = (n & ~31) | (((n >> 2) & 3) << 3) | (((n >> 4) & 1) << 2) | (n & 3);
    wpb[h * 4096 + pn] = wb;    // pi-permuted for flash's l B-frag
  }
}

// ---------------- QKV GEMM: 64x128 tile, BK=64, 512 thr, async dbuf ---------
// Q cols (<512) pre-scaled by 0.125*log2e; V cols pre-multiplied by w~ and
// written transposed+pi-permuted to vtp[d][4096] via an LDS transpose buffer
// (coalesced us8 stores instead of 64-lane scattered us4).

__global__ __launch_bounds__(512, 6) void k_gemm_qkv(const u16* __restrict__ A,
                                                     const u16* __restrict__ Bt,
                                                     const float* __restrict__ bias,
                                                     const float* __restrict__ wexp,
                                                     u16* __restrict__ qk,
                                                     u16* __restrict__ vtp) {
  __shared__ __align__(16) u16 smem[24576];  // As 2x4096 @0, Bs 2x8192 @8192
  const int tid = threadIdx.x;
  const int lane = tid & 63, wave = tid >> 6;
  const int colx = lane & 15, quad = lane >> 4;
  const int m0 = blockIdx.y * 64, n0 = blockIdx.x * 128;
  const int wm = wave >> 2, wn = wave & 3;
  const int sc = (lane & 7) ^ ((lane >> 3) & 7);
  const floatx4 fz = {0.f, 0.f, 0.f, 0.f};
  floatx4 acc[2][2];
#pragma unroll
  for (int i = 0; i < 2; ++i)
#pragma unroll
    for (int j = 0; j < 2; ++j) acc[i][j] = fz;

#define PREF_QKV(k0, b)                                                       \
  {                                                                           \
    int rowa = wave * 8 + (lane >> 3);                                        \
    gld16(&A[(size_t)(m0 + rowa) * 512 + (k0) + sc * 8],                      \
          &smem[(b) * 4096 + wave * 512 + lane * 8]);                         \
    _Pragma("unroll") for (int c = 0; c < 2; ++c) {                           \
      int rowb = wave * 16 + c * 8 + (lane >> 3);                             \
      gld16(&Bt[(size_t)(n0 + rowb) * 512 + (k0) + sc * 8],                   \
            &smem[8192 + (b) * 8192 + wave * 1024 + c * 512 + lane * 8]);     \
    }                                                                         \
  }

  PREF_QKV(0, 0);
  __syncthreads();
  for (int it = 0; it < 8; ++it) {
    int cur = it & 1;
    if (it < 7) PREF_QKV((it + 1) * 64, cur ^ 1);
    const u16* As = &smem[cur * 4096];
    const u16* Bs = &smem[8192 + cur * 8192];
#pragma unroll
    for (int kk = 0; kk < 2; ++kk) {
      short8 af[2], bf[2];
#pragma unroll
      for (int i = 0; i < 2; ++i) {
        int row = wm * 32 + i * 16 + colx;
        af[i] = *(const short8*)&As[row * 64 + (((kk * 4 + quad) ^ (colx & 7))) * 8];
      }
#pragma unroll
      for (int j = 0; j < 2; ++j) {
        int row = wn * 32 + j * 16 + colx;
        bf[j] = *(const short8*)&Bs[row * 64 + (((kk * 4 + quad) ^ (colx & 7))) * 8];
      }
#pragma unroll
      for (int i = 0; i < 2; ++i)
#pragma unroll
        for (int j = 0; j < 2; ++j)
          acc[i][j] = __builtin_amdgcn_mfma_f32_16x16x32_bf16(af[i], bf[j], acc[i][j], 0, 0, 0);
    }
    __syncthreads();
  }

  const bool isV = (blockIdx.x >= 8);
  if (!isV) {
#pragma unroll
    for (int j = 0; j < 2; ++j) {
      int c = n0 + wn * 32 + j * 16 + colx;
      float bq = bias[c];
      float qs = (c < 512) ? 0.18033688011112042f : 1.0f;  // 0.125*log2(e)
#pragma unroll
      for (int i = 0; i < 2; ++i)
#pragma unroll
        for (int r = 0; r < 4; ++r) {
          int row = m0 + wm * 32 + i * 16 + quad * 4 + r;
          qk[(size_t)row * 1024 + c] = f2b((acc[i][j][r] + bq) * qs);
        }
    }
  } else {
    // V: w~-fold + transpose + pi through LDS, then coalesced us8 stores.
    const int dv = n0 - 1024;
    u16* Vl = smem;  // [128 d][72] u16 (stride 144B == 16 mod 128: staggered)
    const int hh = (dv + wn * 32) >> 6;  // GLOBAL head (R12 fix); same for j=0,1
#pragma unroll
    for (int j = 0; j < 2; ++j) {
      float bq = bias[n0 + wn * 32 + j * 16 + colx];
#pragma unroll
      for (int i = 0; i < 2; ++i) {
        floatx4 wv = *(const floatx4*)&wexp[hh * 4096 + m0 + wm * 32 + i * 16 + quad * 4];
        us4 o;
#pragma unroll
        for (int r = 0; r < 4; ++r) o[r] = f2b((acc[i][j][r] + bq) * wv[r]);
        int dl = wn * 32 + j * 16 + colx;          // local d 0..127
        int nc = wm * 32 + quad * 8 + i * 4;       // pi-permuted local n
        *(us4*)&Vl[dl * 72 + nc] = o;
      }
    }
    __syncthreads();
#pragma unroll
    for (int t = 0; t < 2; ++t) {
      int idx = t * 512 + tid;
      int dl = idx >> 3, ch = idx & 7;
      *(us8*)&vtp[(size_t)(dv + dl) * 4096 + m0 + ch * 8] =
          *(const us8*)&Vl[dl * 72 + ch * 8];
    }
  }
#undef PREF_QKV
}

// ---------------- flash (fixed-max, linear, KV-split x2, w-folded) ----------
// grid (64 q-tiles, 8 heads, 2 kv-splits), 512 thr = 8 waves = 4 ih x 2 jq.
// x2-unrolled body: compile-time buffer offsets; incremental global pointers.

__global__ __launch_bounds__(512, 8) void k_flash(const u16* __restrict__ qk,
                                                  const u16* __restrict__ vt,
                                                  const u16* __restrict__ wpb,
                                                  float* __restrict__ opart,
                                                  float* __restrict__ lpart) {
  __shared__ __align__(16) u16 smem[20480];  // 40960 B exactly (4 blocks/CU)
  float* bufs = (float*)smem;                // epilogue overlay 4 x 16x65 f32

  const int tid = threadIdx.x;
  const int lane = tid & 63, wave = tid >> 6;
  const int colx = lane & 15, quad = lane >> 4;
  const int ih = wave >> 1, jq = wave & 1;
  const int q0 = blockIdx.x * 64;
  const int h = blockIdx.y;
  const int z = blockIdx.z;
  const int kvb = z * 2048;
  const floatx4 fz = {0.f, 0.f, 0.f, 0.f};

  const int sc = (lane & 7) ^ ((lane >> 3) & 7);
  const int srow = wave * 8 + (lane >> 3);

  // stage Q (swizzled ds_write) + prefetch tile 0
  {
    int row = tid >> 3, ch = tid & 7;
    *(us8*)&smem[row * 64 + (ch ^ (row & 7)) * 8] =
        *(const us8*)&qk[(size_t)(q0 + row) * 1024 + h * 64 + ch * 8];
  }
  const u16* qptr = qk + (size_t)(kvb + srow) * 1024 + 512 + h * 64 + sc * 8;
  const u16* vptr = vt + (size_t)(h * 64 + srow) * 4096 + kvb + sc * 8;
  const u16* wptr = wpb + h * 4096 + kvb + jq * 32 + quad * 8;
  gld16(qptr, &smem[4096 + wave * 512 + lane * 8]);
  gld16(vptr, &smem[12288 + wave * 512 + lane * 8]);
  qptr += 65536;  // 64 kv rows * 1024
  vptr += 64;     // 64 kv cols
  __syncthreads();

  short8 qf[2];
#pragma unroll
  for (int kk = 0; kk < 2; ++kk) {
    int row = ih * 16 + colx;
    qf[kk] = *(const short8*)&smem[row * 64 + (((kk * 4 + quad) ^ (colx & 7))) * 8];
  }

  floatx4 oacc[4], lacc = fz;
#pragma unroll
  for (int cb = 0; cb < 4; ++cb) oacc[cb] = fz;

#define FBODY(CUR, PREF)                                                      \
  {                                                                           \
    short8 wf = *(const short8*)wptr;                                         \
    wptr += 64;                                                               \
    if (PREF) {                                                               \
      gld16(qptr, &smem[4096 + (1 - (CUR)) * 4096 + wave * 512 + lane * 8]);  \
      gld16(vptr, &smem[12288 + (1 - (CUR)) * 4096 + wave * 512 + lane * 8]); \
      qptr += 65536;                                                          \
      vptr += 64;                                                             \
    }                                                                         \
    const u16* Ks = &smem[4096 + (CUR) * 4096];                               \
    const u16* Vts = &smem[12288 + (CUR) * 4096];                             \
    floatx4 sacc[2] = {fz, fz};                                               \
    _Pragma("unroll") for (int j2 = 0; j2 < 2; ++j2) {                        \
      _Pragma("unroll") for (int kk = 0; kk < 2; ++kk) {                      \
        int row = jq * 32 + j2 * 16 + colx;                                   \
        short8 kf = *(const short8*)&Ks[row * 64 +                            \
                                        (((kk * 4 + quad) ^ (colx & 7))) * 8];\
        sacc[j2] =                                                            \
            __builtin_amdgcn_mfma_f32_16x16x32_bf16(kf, qf[kk], sacc[j2], 0, 0, 0); \
      }                                                                       \
    }                                                                         \
    union { uint32_t w[4]; short8 s; } pk;                                    \
    _Pragma("unroll") for (int j2 = 0; j2 < 2; ++j2) {                        \
      float p0 = fexp2(sacc[j2][0]);                                          \
      float p1 = fexp2(sacc[j2][1]);                                          \
      float p2 = fexp2(sacc[j2][2]);                                          \
      float p3 = fexp2(sacc[j2][3]);                                          \
      pk.w[j2 * 2 + 0] = pkbf16(p0, p1);                                      \
      pk.w[j2 * 2 + 1] = pkbf16(p2, p3);                                      \
    }                                                                         \
    _Pragma("unroll") for (int cb = 0; cb < 4; ++cb) {                        \
      int row = cb * 16 + colx;                                               \
      short8 vf = *(const short8*)&Vts[row * 64 +                             \
                                       (((jq * 4 + quad) ^ (colx & 7))) * 8]; \
      oacc[cb] =                                                              \
          __builtin_amdgcn_mfma_f32_16x16x32_bf16(pk.s, vf, oacc[cb], 0, 0, 0); \
    }                                                                         \
    lacc = __builtin_amdgcn_mfma_f32_16x16x32_bf16(pk.s, wf, lacc, 0, 0, 0);  \
    __syncthreads();                                                          \
  }

  for (int t = 0; t < 15; ++t) {
    FBODY(0, 1)
    FBODY(1, 1)
  }
  FBODY(0, 1)
  FBODY(1, 0)
#undef FBODY

  // cross-jq: jq==1 writes O,l to LDS; jq==0 adds and stores partials.
  float* b = bufs + ih * 1040;
  if (jq == 1) {
#pragma unroll
    for (int cb = 0; cb < 4; ++cb)
#pragma unroll
      for (int r = 0; r < 4; ++r)
        b[(quad * 4 + r) * 65 + cb * 16 + colx] = oacc[cb][r];
    if (colx == 0)
#pragma unroll
      for (int r = 0; r < 4; ++r) b[(quad * 4 + r) * 65 + 64] = lacc[r];
  }
  __syncthreads();
  if (jq == 0) {
#pragma unroll
    for (int cb = 0; cb < 4; ++cb)
#pragma unroll
      for (int r = 0; r < 4; ++r)
        oacc[cb][r] += b[(quad * 4 + r) * 65 + cb * 16 + colx];
#pragma unroll
    for (int r = 0; r < 4; ++r) lacc[r] += b[(quad * 4 + r) * 65 + 64];
    float* op = opart + (size_t)z * 2097152;
#pragma unroll
    for (int cb = 0; cb < 4; ++cb)
#pragma unroll
      for (int r = 0; r < 4; ++r)
        op[(size_t)(q0 + ih * 16 + quad * 4 + r) * 512 + h * 64 + cb * 16 + colx] =
            oacc[cb][r];
    if (colx == 0)
#pragma unroll
      for (int r = 0; r < 4; ++r)
        lpart[z * 32768 + h * 4096 + q0 + ih * 16 + quad * 4 + r] = lacc[r];
  }
}

// ---------------- combine: ao = (O0+O1)/(l0+l1), bf16 ----------------

__global__ __launch_bounds__(256) void k_comb(const float* __restrict__ opart,
                                              const float* __restrict__ lpart,
                                              u16* __restrict__ ao) {
  int idx = blockIdx.x * 256 + threadIdx.x;     // 524288 = 4096 * 128
  int n = idx >> 7, d4 = idx & 127;
  int h = d4 >> 4;
  float l = lpart[h * 4096 + n] + lpart[32768 + h * 4096 + n];
  float inv = 1.0f / l;
  float4 o0 = *(const float4*)&opart[(size_t)n * 512 + d4 * 4];
  float4 o1 = *(const float4*)&opart[2097152 + (size_t)n * 512 + d4 * 4];
  us4 o;
  o[0] = f2b((o0.x + o1.x) * inv);
  o[1] = f2b((o0.y + o1.y) * inv);
  o[2] = f2b((o0.z + o1.z) * inv);
  o[3] = f2b((o0.w + o1.w) * inv);
  *(us4*)&ao[(size_t)n * 512 + d4 * 4] = o;
}

// ---------------- out GEMM: 64x64 tile, BK=64, 512 thr, async dbuf ----------

__global__ __launch_bounds__(512, 4) void k_gemm_out(const u16* __restrict__ A,
                                                     const u16* __restrict__ Bt,
                                                     const float* __restrict__ bias,
                                                     float* __restrict__ Cout) {
  __shared__ __align__(16) u16 smem[16384];  // As 2x4096 @0, Bs 2x4096 @8192
  const int tid = threadIdx.x;
  const int lane = tid & 63, wave = tid >> 6;
  const int colx = lane & 15, quad = lane >> 4;
  const int m0 = blockIdx.y * 64, n0 = blockIdx.x * 64;
  const int wm = wave >> 2, wn = wave & 3;
  const int sc = (lane & 7) ^ ((lane >> 3) & 7);
  const floatx4 fz = {0.f, 0.f, 0.f, 0.f};
  floatx4 acc[2];
  acc[0] = fz; acc[1] = fz;

#define PREF_OUT(k0, b)                                                       \
  {                                                                           \
    int rowa = wave * 8 + (lane >> 3);                                        \
    gld16(&A[(size_t)(m0 + rowa) * 512 + (k0) + sc * 8],                      \
          &smem[(b) * 4096 + wave * 512 + lane * 8]);                         \
    gld16(&Bt[(size_t)(n0 + rowa) * 512 + (k0) + sc * 8],                     \
          &smem[8192 + (b) * 4096 + wave * 512 + lane * 8]);                  \
  }

  PREF_OUT(0, 0);
  __syncthreads();
  for (int it = 0; it < 8; ++it) {
    int cur = it & 1;
    if (it < 7) PREF_OUT((it + 1) * 64, cur ^ 1);
    const u16* As = &smem[cur * 4096];
    const u16* Bs = &smem[8192 + cur * 4096];
#pragma unroll
    for (int kk = 0; kk < 2; ++kk) {
      short8 af[2], bf;
#pragma unroll
      for (int i = 0; i < 2; ++i) {
        int row = wm * 32 + i * 16 + colx;
        af[i] = *(const short8*)&As[row * 64 + (((kk * 4 + quad) ^ (colx & 7))) * 8];
      }
      {
        int row = wn * 16 + colx;
        bf = *(const short8*)&Bs[row * 64 + (((kk * 4 + quad) ^ (colx & 7))) * 8];
      }
#pragma unroll
      for (int i = 0; i < 2; ++i)
        acc[i] = __builtin_amdgcn_mfma_f32_16x16x32_bf16(af[i], bf, acc[i], 0, 0, 0);
    }
    __syncthreads();
  }
  int c = n0 + wn * 16 + colx;
  float bq = bias[c];
#pragma unroll
  for (int i = 0; i < 2; ++i)
#pragma unroll
    for (int r = 0; r < 4; ++r) {
      int row = m0 + wm * 32 + i * 16 + quad * 4 + r;
      Cout[(size_t)row * 512 + c] = acc[i][r] + bq;
    }
#undef PREF_OUT
}

// ---------------- launch ----------------

extern "C" void kernel_launch(void* const* d_in, const int* in_sizes, int n_in,
                              void* d_out, int out_size, void* d_ws, size_t ws_size,
                              hipStream_t stream) {
  const float* x     = (const float*)d_in[0];
  const float* pe    = (const float*)d_in[1];
  const float* w_qkv = (const float*)d_in[2];
  const float* b_qkv = (const float*)d_in[3];
  const float* w_pe  = (const float*)d_in[4];
  const float* b_pe  = (const float*)d_in[5];
  const float* w_out = (const float*)d_in[6];
  const float* b_out = (const float*)d_in[7];
  float* out = (float*)d_out;

  // workspace layout
  u16* xb    = (u16*)d_ws;              // 4096*512
  u16* wqkvT = xb    + 2097152;         // 1536*512
  u16* woutT = wqkvT + 786432;          // 512*512
  u16* qk    = woutT + 262144;          // 4096*1024 (Q'|K)
  u16* vt    = qk    + 4194304;         // 512*4096 (pi-permuted w~-folded V'^T)
  u16* wpb   = vt    + 2097152;         // 8*4096 bf16 (pi-permuted w~)
  u16* ao    = wpb   + 32768;           // 4096*512 bf16
  float* wexp  = (float*)(ao + 2097152); // 8*4096 f32 (same w~, expanded)
  float* opart = wexp + 32768;          // 2 * 4096*512 f32
  float* lpart = opart + 4194304;       // 2 * 8*4096 f32

  k_prep<<<3200, 256, 0, stream>>>(x, xb, w_qkv, wqkvT, w_out, woutT,
                                   pe, w_pe, b_pe, wexp, wpb);
  k_gemm_qkv<<<dim3(12, 64), 512, 0, stream>>>(xb, wqkvT, b_qkv, wexp, qk, vt);
  k_flash<<<dim3(64, 8, 2), 512, 0, stream>>>(qk, vt, wpb, opart, lpart);
  k_comb<<<2048, 256, 0, stream>>>(opart, lpart, ao);
  k_gemm_out<<<dim3(8, 64), 512, 0, stream>>>(ao, woutT, b_out, out);
}